// Round 4
// baseline (236.407 us; speedup 1.0000x reference)
//
#include <hip/hip_runtime.h>
#include <math.h>

#define B_ 128
#define T_ 256
#define N_ 16
#define K_ 10
#define H_ 20
#define TN_ 4096     // T_*N_
#define TQ_ 128      // T_/2 : t-pairs per k

#define REP20(F) F(0) F(1) F(2) F(3) F(4) F(5) F(6) F(7) F(8) F(9) \
                 F(10) F(11) F(12) F(13) F(14) F(15) F(16) F(17) F(18) F(19)

__device__ __forceinline__ float wsum(float v)
{
#pragma unroll
    for (int off = 32; off; off >>= 1) v += __shfl_xor(v, off);
    return v;
}

// ---------------------------------------------------------------------------
// ONE fused kernel. Block = (k, t-pair). 256 threads = 4 waves.
//  P0: stage x[:, 2 t's, :] (4096 floats) into LDS, transposed to [col][b].
//  P1: standardize the 32 (t,n) columns over b (ddof=1, no eps), in place.
//  P2: each wave runs the full MLP for one column at a time (2 samples/lane),
//      weights via uniform-address float4 loads (scalar pipe), then
//      standardizes t over b (ddof=1, std+1e-8) via shuffles, writes z to LDS.
//  P3: product over n per (t,b), wave-reduce, 2 atomicAdds per block.
// The product of the 16 marginal means (pure fp32 rounding residue after
// standardization) underflows to 0 in the fp32 reference => penalty = pj^2.
// ---------------------------------------------------------------------------
__global__ __launch_bounds__(256, 3) void k_all(
    const float* __restrict__ x,
    const float* __restrict__ W1, const float* __restrict__ b1,
    const float* __restrict__ W2, const float* __restrict__ b2,
    const float* __restrict__ W3, const float* __restrict__ b3,
    float* __restrict__ out)
{
    __shared__ float xz[32 * 129];      // [col=dt*16+n][b], pad 129
    __shared__ float zl[32 * 128];      // [col][b] standardized t
    __shared__ float pjp[4];

    const int tq  = blockIdx.x;         // 0..127 (t-pair)
    const int k   = blockIdx.y;         // 0..9
    const int tid = threadIdx.x;
    const int wv  = tid >> 6;
    const int l   = tid & 63;

    // ---- P0: stage x (coalesced float4), transpose to [col][b] ----
#pragma unroll
    for (int r = 0; r < 4; ++r) {
        const int g4 = r * 1024 + tid * 4;
        const int b  = g4 >> 5;
        const int d0 = g4 & 31;
        const float4 v = *reinterpret_cast<const float4*>(x + b * TN_ + tq * 32 + d0);
        xz[(d0 + 0) * 129 + b] = v.x;
        xz[(d0 + 1) * 129 + b] = v.y;
        xz[(d0 + 2) * 129 + b] = v.z;
        xz[(d0 + 3) * 129 + b] = v.w;
    }
    __syncthreads();

    // ---- P1: standardize columns over b (ddof=1, no eps) ----
#pragma unroll
    for (int c = 0; c < 8; ++c) {
        const int col = wv * 8 + c;
        const float a0 = xz[col * 129 + l];
        const float a1 = xz[col * 129 + 64 + l];
        const float mu = wsum(a0 + a1) * (1.f / 128.f);
        const float d0 = a0 - mu, d1 = a1 - mu;
        const float r  = __builtin_amdgcn_rsqf(wsum(fmaf(d0, d0, d1 * d1)) * (1.f / 127.f));
        xz[col * 129 + l]      = d0 * r;
        xz[col * 129 + 64 + l] = d1 * r;
    }
    __syncthreads();

    // ---- P2: MLP, one column per wave-iteration, 2 samples per lane ----
#pragma unroll 1
    for (int it = 0; it < 8; ++it) {
        const int col = wv * 8 + it;           // dt = col>>4, n = col&15
        const int kn  = k * 16 + (col & 15);

        const float u0 = xz[col * 129 + l];
        const float u1 = xz[col * 129 + 64 + l];

        const float4* __restrict__ w1v = reinterpret_cast<const float4*>(W1 + kn * 20);
        const float4* __restrict__ b1v = reinterpret_cast<const float4*>(b1 + kn * 20);
        const float4* __restrict__ w2v = reinterpret_cast<const float4*>(W2 + kn * 400);
        const float4* __restrict__ b2v = reinterpret_cast<const float4*>(b2 + kn * 20);
        const float4* __restrict__ w3v = reinterpret_cast<const float4*>(W3 + kn * 20);
        const float  bb3 = b3[kn];

        // Layer 1 + ReLU
#define DECLH(i) float ha##i, hb##i;
        REP20(DECLH)
        float s1a = 0.f, s1b = 0.f;
#define L1C(c,i0,i1,i2,i3) { const float4 w = w1v[c]; const float4 bb = b1v[c]; \
        ha##i0 = fmaxf(fmaf(u0, w.x, bb.x), 0.f); hb##i0 = fmaxf(fmaf(u1, w.x, bb.x), 0.f); s1a += ha##i0; s1b += hb##i0; \
        ha##i1 = fmaxf(fmaf(u0, w.y, bb.y), 0.f); hb##i1 = fmaxf(fmaf(u1, w.y, bb.y), 0.f); s1a += ha##i1; s1b += hb##i1; \
        ha##i2 = fmaxf(fmaf(u0, w.z, bb.z), 0.f); hb##i2 = fmaxf(fmaf(u1, w.z, bb.z), 0.f); s1a += ha##i2; s1b += hb##i2; \
        ha##i3 = fmaxf(fmaf(u0, w.w, bb.w), 0.f); hb##i3 = fmaxf(fmaf(u1, w.w, bb.w), 0.f); s1a += ha##i3; s1b += hb##i3; }
        L1C(0,0,1,2,3) L1C(1,4,5,6,7) L1C(2,8,9,10,11) L1C(3,12,13,14,15) L1C(4,16,17,18,19)

        // LayerNorm 1
        const float mu1a = s1a * 0.05f, mu1b = s1b * 0.05f;
        float v1a = 0.f, v1b = 0.f;
#define VAR1(i) { float d = ha##i - mu1a; v1a = fmaf(d, d, v1a); d = hb##i - mu1b; v1b = fmaf(d, d, v1b); }
        REP20(VAR1)
        const float r1a = __builtin_amdgcn_rsqf(v1a * 0.05f + 1e-5f);
        const float r1b = __builtin_amdgcn_rsqf(v1b * 0.05f + 1e-5f);
        const float m1a = mu1a * r1a, m1b = mu1b * r1b;
#define NRM1(i) ha##i = fmaf(ha##i, r1a, -m1a); hb##i = fmaf(hb##i, r1b, -m1b);
        REP20(NRM1)

        // Layer 2 (20x20) + ReLU
#define DECLG(i) float ga##i, gb##i;
        REP20(DECLG)
        float s2a = 0.f, s2b = 0.f;
#define L2C(o,c,i0,i1,i2,i3) { const float4 w = w2v[(o) * 5 + (c)]; \
        acca = fmaf(ha##i0, w.x, acca); acca = fmaf(ha##i1, w.y, acca); \
        acca = fmaf(ha##i2, w.z, acca); acca = fmaf(ha##i3, w.w, acca); \
        accb = fmaf(hb##i0, w.x, accb); accb = fmaf(hb##i1, w.y, accb); \
        accb = fmaf(hb##i2, w.z, accb); accb = fmaf(hb##i3, w.w, accb); }
#define L2ROW(o,bo) { float acca = (bo), accb = (bo); \
        L2C(o,0,0,1,2,3) L2C(o,1,4,5,6,7) L2C(o,2,8,9,10,11) \
        L2C(o,3,12,13,14,15) L2C(o,4,16,17,18,19) \
        ga##o = fmaxf(acca, 0.f); s2a += ga##o; gb##o = fmaxf(accb, 0.f); s2b += gb##o; }
        {
            const float4 b2c0 = b2v[0], b2c1 = b2v[1], b2c2 = b2v[2], b2c3 = b2v[3], b2c4 = b2v[4];
            L2ROW(0,  b2c0.x) L2ROW(1,  b2c0.y) L2ROW(2,  b2c0.z) L2ROW(3,  b2c0.w)
            L2ROW(4,  b2c1.x) L2ROW(5,  b2c1.y) L2ROW(6,  b2c1.z) L2ROW(7,  b2c1.w)
            L2ROW(8,  b2c2.x) L2ROW(9,  b2c2.y) L2ROW(10, b2c2.z) L2ROW(11, b2c2.w)
            L2ROW(12, b2c3.x) L2ROW(13, b2c3.y) L2ROW(14, b2c3.z) L2ROW(15, b2c3.w)
            L2ROW(16, b2c4.x) L2ROW(17, b2c4.y) L2ROW(18, b2c4.z) L2ROW(19, b2c4.w)
        }

        // LayerNorm 2 fused into layer-3 dot
        const float mu2a = s2a * 0.05f, mu2b = s2b * 0.05f;
        float v2a = 0.f, v2b = 0.f;
#define VAR2(i) { float d = ga##i - mu2a; v2a = fmaf(d, d, v2a); d = gb##i - mu2b; v2b = fmaf(d, d, v2b); }
        REP20(VAR2)
        const float r2a = __builtin_amdgcn_rsqf(v2a * 0.05f + 1e-5f);
        const float r2b = __builtin_amdgcn_rsqf(v2b * 0.05f + 1e-5f);
        const float m2a = mu2a * r2a, m2b = mu2b * r2b;

        float t0 = bb3, t1 = bb3;
#define L3C(c,i0,i1,i2,i3) { const float4 w = w3v[c]; \
        t0 = fmaf(fmaf(ga##i0, r2a, -m2a), w.x, t0); t1 = fmaf(fmaf(gb##i0, r2b, -m2b), w.x, t1); \
        t0 = fmaf(fmaf(ga##i1, r2a, -m2a), w.y, t0); t1 = fmaf(fmaf(gb##i1, r2b, -m2b), w.y, t1); \
        t0 = fmaf(fmaf(ga##i2, r2a, -m2a), w.z, t0); t1 = fmaf(fmaf(gb##i2, r2b, -m2b), w.z, t1); \
        t0 = fmaf(fmaf(ga##i3, r2a, -m2a), w.w, t0); t1 = fmaf(fmaf(gb##i3, r2b, -m2b), w.w, t1); }
        L3C(0,0,1,2,3) L3C(1,4,5,6,7) L3C(2,8,9,10,11) L3C(3,12,13,14,15) L3C(4,16,17,18,19)

        // standardize t over b (ddof=1, std+1e-8), write z to LDS
        const float smu = wsum(t0 + t1) * (1.f / 128.f);
        const float e0 = t0 - smu, e1 = t1 - smu;
        const float sd = sqrtf(wsum(fmaf(e0, e0, e1 * e1)) * (1.f / 127.f));
        const float rr = 1.f / (sd + 1e-8f);
        zl[col * 128 + l]      = e0 * rr;
        zl[col * 128 + 64 + l] = e1 * rr;
    }
    __syncthreads();

    // ---- P3: joint products; penalty = pj^2 ----
    {
        const int t_loc = wv >> 1;          // waves 0,1 -> t0; 2,3 -> t1
        const int b     = (wv & 1) * 64 + l;
        float pj = zl[(t_loc * 16 + 0) * 128 + b];
#pragma unroll
        for (int n = 1; n < 16; ++n) pj *= zl[(t_loc * 16 + n) * 128 + b];
        const float ps = wsum(pj);
        if (l == 0) pjp[wv] = ps;
    }
    __syncthreads();
    if (tid < 2) {
        const float pjm = (pjp[tid * 2] + pjp[tid * 2 + 1]) * (1.f / 128.f);
        atomicAdd(out, pjm * pjm * (1.f / (K_ * T_)));
    }
}

// ---------------------------------------------------------------------------
extern "C" void kernel_launch(void* const* d_in, const int* in_sizes, int n_in,
                              void* d_out, int out_size, void* d_ws, size_t ws_size,
                              hipStream_t stream)
{
    const float* x  = (const float*)d_in[0];
    const float* W1 = (const float*)d_in[1];
    const float* b1 = (const float*)d_in[2];
    const float* W2 = (const float*)d_in[3];
    const float* b2 = (const float*)d_in[4];
    const float* W3 = (const float*)d_in[5];
    const float* b3 = (const float*)d_in[6];
    float* out = (float*)d_out;

    hipMemsetAsync(out, 0, sizeof(float), stream);

    dim3 grid(TQ_, K_);                 // 128 t-pairs x 10 k
    k_all<<<grid, 256, 0, stream>>>(x, W1, b1, W2, b2, W3, b3, out);
}